// Round 2
// baseline (1679.200 us; speedup 1.0000x reference)
//
#include <hip/hip_runtime.h>
#include <math.h>

#define B_CUR 4096
#define N_TOT 8192
#define C_F   256
#define C_TOT 288
#define KSEL  16

// K1: feature row norms -> normalized (x sqrt(0.95)) fp32 rows of Z; copy raw feats out.
__global__ __launch_bounds__(256) void k_prep_feats(
    const float* __restrict__ feats, const float* __restrict__ hfeats,
    float* __restrict__ Z, float* __restrict__ out_nf) {
  int wave = threadIdx.x >> 6;
  int lane = threadIdx.x & 63;
  int row  = blockIdx.x * 4 + wave;
  const float* src = (row < B_CUR) ? (feats + (size_t)row * C_F)
                                   : (hfeats + (size_t)(row - B_CUR) * C_F);
  int c0 = lane * 4;
  float4 raw = *(const float4*)(src + c0);
  float ss = raw.x*raw.x + raw.y*raw.y + raw.z*raw.z + raw.w*raw.w;
  #pragma unroll
  for (int m = 32; m; m >>= 1) ss += __shfl_xor(ss, m, 64);
  float norm  = sqrtf(ss);
  float scale = 0.97467943448089633f / fmaxf(norm, 1e-12f);   // sqrt(0.95)
  float4 o = make_float4(raw.x*scale, raw.y*scale, raw.z*scale, raw.w*scale);
  *(float4*)(Z + (size_t)row * C_TOT + c0) = o;
  *(float4*)(out_nf + (size_t)row * C_F + c0) = raw;
}

// K2: positional encoding (4 dims x freqs {1,2,4,8} x sin/cos), normalized x sqrt(0.05).
__global__ void k_prep_pos(const float* __restrict__ coords,
                           const float* __restrict__ hcoords,
                           float* __restrict__ Z) {
  int r = blockIdx.x * blockDim.x + threadIdx.x;
  if (r >= N_TOT) return;
  const float* src = (r < B_CUR) ? (coords + (size_t)r * 4)
                                 : (hcoords + (size_t)(r - B_CUR) * 4);
  float pe[32];
  float ss = 0.f;
  #pragma unroll
  for (int d = 0; d < 4; ++d) {
    float c = src[d];
    float base = c * 6.283185307179586f;
    #pragma unroll
    for (int f = 0; f < 4; ++f) {
      float ang = base * (float)(1 << f);
      float s = sinf(ang), co = cosf(ang);
      pe[d*8 + f]     = s;
      pe[d*8 + 4 + f] = co;
      ss += s*s + co*co;
    }
  }
  float scale = 0.22360679774997896f / fmaxf(sqrtf(ss), 1e-12f); // sqrt(0.05)
  float* dst = Z + (size_t)r * C_TOT + C_F;
  #pragma unroll
  for (int k = 0; k < 32; ++k) dst[k] = pe[k] * scale;
}

// K3: S = Z Z^T (64x64 tile, BK=32, fp32), cross weight applied, store fp32 into d_out.
#define BK 32
__global__ __launch_bounds__(256) void k_gemm(const float* __restrict__ Z,
                                              float* __restrict__ out) {
  __shared__ float As[BK * 68];
  __shared__ float Bs[BK * 68];
  int tid = threadIdx.x;
  int bi = blockIdx.y, bj = blockIdx.x;
  int tx = tid & 15, ty = tid >> 4;
  float acc[4][4] = {};
  const float* Arow = Z + (size_t)(bi * 64) * C_TOT;
  const float* Brow = Z + (size_t)(bj * 64) * C_TOT;
  for (int kt = 0; kt < C_TOT; kt += BK) {
    #pragma unroll
    for (int it = 0; it < 2; ++it) {
      int idx = tid + it * 256;      // 0..511
      int row = idx >> 3;            // 0..63
      int c4  = (idx & 7) << 2;      // 0,4,..,28
      float4 a = *(const float4*)(Arow + (size_t)row * C_TOT + kt + c4);
      float4 b = *(const float4*)(Brow + (size_t)row * C_TOT + kt + c4);
      As[(c4+0)*68 + row] = a.x; As[(c4+1)*68 + row] = a.y;
      As[(c4+2)*68 + row] = a.z; As[(c4+3)*68 + row] = a.w;
      Bs[(c4+0)*68 + row] = b.x; Bs[(c4+1)*68 + row] = b.y;
      Bs[(c4+2)*68 + row] = b.z; Bs[(c4+3)*68 + row] = b.w;
    }
    __syncthreads();
    #pragma unroll
    for (int k = 0; k < BK; ++k) {
      float4 av = *(const float4*)&As[k*68 + ty*4];
      float4 bv = *(const float4*)&Bs[k*68 + tx*4];
      float a_[4] = {av.x, av.y, av.z, av.w};
      float b_[4] = {bv.x, bv.y, bv.z, bv.w};
      #pragma unroll
      for (int i = 0; i < 4; ++i)
        #pragma unroll
        for (int j = 0; j < 4; ++j)
          acc[i][j] += a_[i] * b_[j];
    }
    __syncthreads();
  }
  float w = ((bi < 64) != (bj < 64)) ? 0.5f : 1.0f;
  #pragma unroll
  for (int i = 0; i < 4; ++i) {
    int gr = bi*64 + ty*4 + i;
    int gc = bj*64 + tx*4;
    float4 st = make_float4(acc[i][0]*w, acc[i][1]*w, acc[i][2]*w, acc[i][3]*w);
    *(float4*)(out + (size_t)gr * N_TOT + gc) = st;
  }
}

// K4: per-row top-16 (diag forced max, ties -> lowest index), record (idx,val,deg),
//     then zero the whole row. One block per row; winner-thread-only rescan.
__global__ __launch_bounds__(256) void k_topk(
    const float* __restrict__ adj, float* __restrict__ adj_w,
    int* __restrict__ topk_idx, float* __restrict__ topk_val,
    float* __restrict__ deg_out) {
  __shared__ float sv[4];
  __shared__ int   si[4];
  int r = blockIdx.x;
  int t = threadIdx.x;
  const float* rowp = adj + (size_t)r * N_TOT;

  unsigned int taken = 0;
  float bv = -INFINITY; int bi = 0x7fffffff;
  for (int kk = 0; kk < 32; ++kk) {
    int col = kk*256 + t;
    float v = (col == r) ? INFINITY : rowp[col];
    if (v > bv) { bv = v; bi = col; }   // ascending col scan: strict > keeps lowest idx
  }
  if (bi == 0x7fffffff) { bv = -INFINITY; bi = t; }  // NaN insurance: keep idx valid
  float degacc = 0.f;
  for (int it = 0; it < KSEL; ++it) {
    float rv = bv; int ri = bi;
    #pragma unroll
    for (int m = 32; m; m >>= 1) {
      float ov = __shfl_xor(rv, m, 64);
      int   oi = __shfl_xor(ri, m, 64);
      if (ov > rv || (ov == rv && oi < ri)) { rv = ov; ri = oi; }
    }
    int lane = t & 63, wvid = t >> 6;
    if (lane == 0) { sv[wvid] = rv; si[wvid] = ri; }
    __syncthreads();
    float wv_ = sv[0]; int wi_ = si[0];
    #pragma unroll
    for (int q = 1; q < 4; ++q) {
      float ov = sv[q]; int oi = si[q];
      if (ov > wv_ || (ov == wv_ && oi < wi_)) { wv_ = ov; wi_ = oi; }
    }
    if (wi_ < 0 || wi_ >= N_TOT) wi_ = 0;   // insurance, never taken in healthy runs
    if (t == 0) {
      float val = (wi_ == r) ? rowp[r] : wv_;  // diag keeps original value
      topk_idx[r*KSEL + it] = wi_;
      topk_val[r*KSEL + it] = val;
      degacc += val;
    }
    if (t == (wi_ & 255)) {           // owner marks and rescans its 32 columns
      taken |= 1u << (wi_ >> 8);
      bv = -INFINITY; bi = t;
      bool any = false;
      for (int kk = 0; kk < 32; ++kk) {
        if (taken & (1u << kk)) continue;
        int col = kk*256 + t;
        float v = (col == r) ? INFINITY : rowp[col];
        if (!any || v > bv) { bv = v; bi = col; any = true; }
      }
    }
    __syncthreads();
  }
  if (t == 0) deg_out[r] = degacc;
  // zero the whole row (kept entries rewritten by k_scale)
  const float4 z4 = make_float4(0.f, 0.f, 0.f, 0.f);
  for (int kk = 0; kk < 8; ++kk) {
    *(float4*)(adj_w + (size_t)r * N_TOT + (size_t)(kk*256 + t)*4) = z4;
  }
}

// K5: write kept entries scaled by d^-1/2 on both sides.
__global__ void k_scale(float* __restrict__ adj, const int* __restrict__ topk_idx,
                        const float* __restrict__ topk_val,
                        const float* __restrict__ deg) {
  int g = blockIdx.x * blockDim.x + threadIdx.x;
  if (g >= N_TOT * KSEL) return;
  int r = g >> 4, m = g & 15;
  int j   = topk_idx[r*KSEL + m];
  if (j < 0) j = 0; if (j >= N_TOT) j = N_TOT - 1;  // insurance
  float v = topk_val[r*KSEL + m];
  float di = 1.0f / sqrtf(fmaxf(deg[r], 1e-12f));
  float dj = 1.0f / sqrtf(fmaxf(deg[j], 1e-12f));
  adj[(size_t)r * N_TOT + j] = v * di * dj;
}

extern "C" void kernel_launch(void* const* d_in, const int* in_sizes, int n_in,
                              void* d_out, int out_size, void* d_ws, size_t ws_size,
                              hipStream_t stream) {
  const float* feats   = (const float*)d_in[0];
  const float* coords  = (const float*)d_in[1];
  const float* hfeats  = (const float*)d_in[2];
  const float* hcoords = (const float*)d_in[3];
  float* out    = (float*)d_out;
  float* adj    = out;                               // [8192, 8192] f32
  float* out_nf = out + (size_t)N_TOT * N_TOT;       // [8192, 256]  f32

  char*  ws     = (char*)d_ws;
  float* Z      = (float*)ws;                                      // 8192*288 f32 (9.4 MB)
  size_t zb     = (size_t)N_TOT * C_TOT * sizeof(float);
  int*   t_idx  = (int*)(ws + zb);                                 // 8192*16 int
  float* t_val  = (float*)(ws + zb + (size_t)N_TOT*KSEL*sizeof(int));
  float* deg    = (float*)(ws + zb + (size_t)N_TOT*KSEL*(sizeof(int)+sizeof(float)));

  hipLaunchKernelGGL(k_prep_feats, dim3(N_TOT/4), dim3(256), 0, stream,
                     feats, hfeats, Z, out_nf);
  hipLaunchKernelGGL(k_prep_pos, dim3(N_TOT/256), dim3(256), 0, stream,
                     coords, hcoords, Z);
  hipLaunchKernelGGL(k_gemm, dim3(128, 128), dim3(256), 0, stream, Z, adj);
  hipLaunchKernelGGL(k_topk, dim3(N_TOT), dim3(256), 0, stream,
                     adj, adj, t_idx, t_val, deg);
  hipLaunchKernelGGL(k_scale, dim3((N_TOT*KSEL + 255)/256), dim3(256), 0, stream,
                     adj, t_idx, t_val, deg);
}

// Round 3
// 537.409 us; speedup vs baseline: 3.1246x; 3.1246x over previous
//
#include <hip/hip_runtime.h>
#include <math.h>

#define B_CUR 4096
#define N_TOT 8192
#define C_F   256
#define C_TOT 288
#define KSEL  16

typedef unsigned short u16;
typedef __attribute__((ext_vector_type(8))) short short8;
typedef __attribute__((ext_vector_type(4))) float floatx4;

__device__ inline u16 f2bf(float f) {
  union { float f; unsigned int u; } x; x.f = f;
  unsigned int u = x.u;
  u += ((u >> 16) & 1u) + 0x7FFFu;   // RNE
  return (u16)(u >> 16);
}

// K1: normalize feature rows (x sqrt(0.95)) -> bf16 Zb; copy raw feats to out_nf.
__global__ __launch_bounds__(256) void k_prep_feats(
    const float* __restrict__ feats, const float* __restrict__ hfeats,
    u16* __restrict__ Zb, float* __restrict__ out_nf) {
  int wave = threadIdx.x >> 6;
  int lane = threadIdx.x & 63;
  int row  = blockIdx.x * 4 + wave;
  const float* src = (row < B_CUR) ? (feats + (size_t)row * C_F)
                                   : (hfeats + (size_t)(row - B_CUR) * C_F);
  int c0 = lane * 4;
  float4 raw = *(const float4*)(src + c0);
  float ss = raw.x*raw.x + raw.y*raw.y + raw.z*raw.z + raw.w*raw.w;
  #pragma unroll
  for (int m = 32; m; m >>= 1) ss += __shfl_xor(ss, m, 64);
  float scale = 0.97467943448089633f / fmaxf(sqrtf(ss), 1e-12f);   // sqrt(0.95)
  ushort4 o;
  o.x = f2bf(raw.x*scale); o.y = f2bf(raw.y*scale);
  o.z = f2bf(raw.z*scale); o.w = f2bf(raw.w*scale);
  *(ushort4*)(Zb + (size_t)row * C_TOT + c0) = o;
  *(float4*)(out_nf + (size_t)row * C_F + c0) = raw;
}

// K2: positional encoding -> normalized (x sqrt(0.05)) bf16 into Zb[:,256:288].
__global__ void k_prep_pos(const float* __restrict__ coords,
                           const float* __restrict__ hcoords,
                           u16* __restrict__ Zb) {
  int r = blockIdx.x * blockDim.x + threadIdx.x;
  if (r >= N_TOT) return;
  const float* src = (r < B_CUR) ? (coords + (size_t)r * 4)
                                 : (hcoords + (size_t)(r - B_CUR) * 4);
  float pe[32];
  float ss = 0.f;
  #pragma unroll
  for (int d = 0; d < 4; ++d) {
    float base = src[d] * 6.283185307179586f;
    #pragma unroll
    for (int f = 0; f < 4; ++f) {
      float ang = base * (float)(1 << f);
      float s = sinf(ang), co = cosf(ang);
      pe[d*8 + f]     = s;
      pe[d*8 + 4 + f] = co;
      ss += s*s + co*co;
    }
  }
  float scale = 0.22360679774997896f / fmaxf(sqrtf(ss), 1e-12f); // sqrt(0.05)
  u16* dst = Zb + (size_t)r * C_TOT + C_F;
  #pragma unroll
  for (int k = 0; k < 32; ++k) dst[k] = f2bf(pe[k] * scale);
}

// K3: S = Zb Zb^T via bf16 MFMA 16x16x32. 128x128 block tile, BK=32, 4 waves 2x2,
//     each wave 4x4 fragment tiles (64x64). Cross weight in epilogue; fp32 out.
#define LDS_STRIDE 40   // 32 + 8 pad (keeps 16B alignment, breaks bank stride)
__global__ __launch_bounds__(256) void k_gemm_mfma(const u16* __restrict__ Zb,
                                                   float* __restrict__ out) {
  __shared__ u16 As[128 * LDS_STRIDE];
  __shared__ u16 Bs[128 * LDS_STRIDE];
  int tid  = threadIdx.x;
  int bi   = blockIdx.y, bj = blockIdx.x;
  int wave = tid >> 6, lane = tid & 63;
  int quad = lane >> 4, l16 = lane & 15;
  int m0w  = (wave >> 1) * 64;
  int n0w  = (wave & 1) * 64;
  int i0   = bi * 128, j0 = bj * 128;

  floatx4 acc[4][4];
  #pragma unroll
  for (int a = 0; a < 4; ++a)
    #pragma unroll
    for (int b = 0; b < 4; ++b) acc[a][b] = (floatx4){0.f, 0.f, 0.f, 0.f};

  for (int kt = 0; kt < C_TOT; kt += 32) {
    #pragma unroll
    for (int it = 0; it < 2; ++it) {
      int idx = tid + it * 256;            // 0..511
      int row = idx >> 2, seg = idx & 3;   // 16B segment
      uint4 av = *(const uint4*)(Zb + (size_t)(i0 + row) * C_TOT + kt + seg * 8);
      uint4 bv = *(const uint4*)(Zb + (size_t)(j0 + row) * C_TOT + kt + seg * 8);
      *(uint4*)(&As[row * LDS_STRIDE + seg * 8]) = av;
      *(uint4*)(&Bs[row * LDS_STRIDE + seg * 8]) = bv;
    }
    __syncthreads();
    short8 af[4], bf[4];
    #pragma unroll
    for (int mi = 0; mi < 4; ++mi)
      af[mi] = *(const short8*)(&As[(m0w + mi*16 + l16) * LDS_STRIDE + quad * 8]);
    #pragma unroll
    for (int ni = 0; ni < 4; ++ni)
      bf[ni] = *(const short8*)(&Bs[(n0w + ni*16 + l16) * LDS_STRIDE + quad * 8]);
    #pragma unroll
    for (int mi = 0; mi < 4; ++mi)
      #pragma unroll
      for (int ni = 0; ni < 4; ++ni)
        acc[mi][ni] = __builtin_amdgcn_mfma_f32_16x16x32_bf16(
            af[mi], bf[ni], acc[mi][ni], 0, 0, 0);
    __syncthreads();
  }

  float w = ((bi < 32) != (bj < 32)) ? 0.5f : 1.0f;  // cross block weight
  #pragma unroll
  for (int mi = 0; mi < 4; ++mi) {
    #pragma unroll
    for (int ni = 0; ni < 4; ++ni) {
      int row0 = i0 + m0w + mi*16 + quad*4;
      int col  = j0 + n0w + ni*16 + l16;
      #pragma unroll
      for (int rg = 0; rg < 4; ++rg)
        out[(size_t)(row0 + rg) * N_TOT + col] = acc[mi][ni][rg] * w;
    }
  }
}

// K4: per-row top-16 from LDS-staged row. Full rescan each iter, winner -> -INF.
__global__ __launch_bounds__(256) void k_topk(
    const float* __restrict__ adj, float* __restrict__ adj_w,
    int* __restrict__ topk_idx, float* __restrict__ topk_val,
    float* __restrict__ deg_out) {
  __shared__ float rowbuf[N_TOT];
  __shared__ float sv[4];
  __shared__ int   si[4];
  int r = blockIdx.x;
  int t = threadIdx.x;
  const float* rowp = adj + (size_t)r * N_TOT;

  #pragma unroll
  for (int kk = 0; kk < 8; ++kk) {
    float4 v = *(const float4*)(rowp + kk*1024 + t*4);
    *(float4*)(&rowbuf[kk*1024 + t*4]) = v;
  }
  __syncthreads();
  float diagval = 0.f;
  if (t == 0) { diagval = rowbuf[r]; rowbuf[r] = INFINITY; }
  __syncthreads();

  float degacc = 0.f;
  for (int it = 0; it < KSEL; ++it) {
    float bv = -INFINITY; int bi = 0;
    #pragma unroll
    for (int kk = 0; kk < 8; ++kk) {
      int c0 = kk*1024 + t*4;
      float4 v = *(const float4*)(&rowbuf[c0]);
      if (v.x > bv) { bv = v.x; bi = c0;     }
      if (v.y > bv) { bv = v.y; bi = c0 + 1; }
      if (v.z > bv) { bv = v.z; bi = c0 + 2; }
      if (v.w > bv) { bv = v.w; bi = c0 + 3; }
    }
    float rv = bv; int ri = bi;
    #pragma unroll
    for (int m = 32; m; m >>= 1) {
      float ov = __shfl_xor(rv, m, 64);
      int   oi = __shfl_xor(ri, m, 64);
      if (ov > rv || (ov == rv && oi < ri)) { rv = ov; ri = oi; }
    }
    int lane = t & 63, wvid = t >> 6;
    if (lane == 0) { sv[wvid] = rv; si[wvid] = ri; }
    __syncthreads();
    if (t == 0) {
      float wv_ = sv[0]; int wi_ = si[0];
      #pragma unroll
      for (int q = 1; q < 4; ++q) {
        float ov = sv[q]; int oi = si[q];
        if (ov > wv_ || (ov == wv_ && oi < wi_)) { wv_ = ov; wi_ = oi; }
      }
      float val = (wi_ == r) ? diagval : wv_;
      topk_idx[r*KSEL + it] = wi_;
      topk_val[r*KSEL + it] = val;
      degacc += val;
      rowbuf[wi_] = -INFINITY;
    }
    __syncthreads();
  }
  if (t == 0) deg_out[r] = degacc;

  const float4 z4 = make_float4(0.f, 0.f, 0.f, 0.f);
  #pragma unroll
  for (int kk = 0; kk < 8; ++kk)
    *(float4*)(adj_w + (size_t)r * N_TOT + kk*1024 + t*4) = z4;
}

// K5: write kept entries scaled by d^-1/2 on both sides.
__global__ void k_scale(float* __restrict__ adj, const int* __restrict__ topk_idx,
                        const float* __restrict__ topk_val,
                        const float* __restrict__ deg) {
  int g = blockIdx.x * blockDim.x + threadIdx.x;
  if (g >= N_TOT * KSEL) return;
  int r = g >> 4, m = g & 15;
  int j = topk_idx[r*KSEL + m];
  if (j < 0) j = 0; if (j >= N_TOT) j = N_TOT - 1;  // insurance
  float v = topk_val[r*KSEL + m];
  float di = 1.0f / sqrtf(fmaxf(deg[r], 1e-12f));
  float dj = 1.0f / sqrtf(fmaxf(deg[j], 1e-12f));
  adj[(size_t)r * N_TOT + j] = v * di * dj;
}

extern "C" void kernel_launch(void* const* d_in, const int* in_sizes, int n_in,
                              void* d_out, int out_size, void* d_ws, size_t ws_size,
                              hipStream_t stream) {
  const float* feats   = (const float*)d_in[0];
  const float* coords  = (const float*)d_in[1];
  const float* hfeats  = (const float*)d_in[2];
  const float* hcoords = (const float*)d_in[3];
  float* out    = (float*)d_out;
  float* adj    = out;                               // [8192, 8192] f32
  float* out_nf = out + (size_t)N_TOT * N_TOT;       // [8192, 256]  f32

  char* ws    = (char*)d_ws;
  u16*  Zb    = (u16*)ws;                            // 8192*288 bf16 (4.7 MB)
  size_t zb   = (size_t)N_TOT * C_TOT * sizeof(u16);
  zb = (zb + 255) & ~(size_t)255;
  int*   t_idx = (int*)(ws + zb);
  float* t_val = (float*)(ws + zb + (size_t)N_TOT*KSEL*sizeof(int));
  float* deg   = (float*)(ws + zb + (size_t)N_TOT*KSEL*(sizeof(int)+sizeof(float)));

  hipLaunchKernelGGL(k_prep_feats, dim3(N_TOT/4), dim3(256), 0, stream,
                     feats, hfeats, Zb, out_nf);
  hipLaunchKernelGGL(k_prep_pos, dim3(N_TOT/256), dim3(256), 0, stream,
                     coords, hcoords, Zb);
  hipLaunchKernelGGL(k_gemm_mfma, dim3(64, 64), dim3(256), 0, stream, Zb, adj);
  hipLaunchKernelGGL(k_topk, dim3(N_TOT), dim3(256), 0, stream,
                     adj, adj, t_idx, t_val, deg);
  hipLaunchKernelGGL(k_scale, dim3((N_TOT*KSEL + 255)/256), dim3(256), 0, stream,
                     adj, t_idx, t_val, deg);
}

// Round 4
// 510.354 us; speedup vs baseline: 3.2903x; 1.0530x over previous
//
#include <hip/hip_runtime.h>
#include <math.h>

#define B_CUR 4096
#define N_TOT 8192
#define C_F   256
#define C_TOT 288
#define KSEL  16

typedef unsigned short u16;
typedef __attribute__((ext_vector_type(8))) short short8;
typedef __attribute__((ext_vector_type(4))) float floatx4;

__device__ inline float bf2f(u16 v) {
  union { unsigned int u; float f; } x; x.u = ((unsigned int)v) << 16; return x.f;
}
__device__ inline u16 f2bf(float f) {
  union { float f; unsigned int u; } x; x.f = f;
  unsigned int u = x.u;
  u += ((u >> 16) & 1u) + 0x7FFFu;   // RNE
  return (u16)(u >> 16);
}

#define GLD_LDS16(g, l) __builtin_amdgcn_global_load_lds(                      \
    (const __attribute__((address_space(1))) unsigned int*)(g),                \
    (__attribute__((address_space(3))) unsigned int*)(l), 16, 0, 0)

// K1: normalize feature rows (x sqrt(0.95)) -> bf16 Zb; copy raw feats to out_nf.
__global__ __launch_bounds__(256) void k_prep_feats(
    const float* __restrict__ feats, const float* __restrict__ hfeats,
    u16* __restrict__ Zb, float* __restrict__ out_nf) {
  int wave = threadIdx.x >> 6;
  int lane = threadIdx.x & 63;
  int row  = blockIdx.x * 4 + wave;
  const float* src = (row < B_CUR) ? (feats + (size_t)row * C_F)
                                   : (hfeats + (size_t)(row - B_CUR) * C_F);
  int c0 = lane * 4;
  float4 raw = *(const float4*)(src + c0);
  float ss = raw.x*raw.x + raw.y*raw.y + raw.z*raw.z + raw.w*raw.w;
  #pragma unroll
  for (int m = 32; m; m >>= 1) ss += __shfl_xor(ss, m, 64);
  float scale = 0.97467943448089633f / fmaxf(sqrtf(ss), 1e-12f);   // sqrt(0.95)
  ushort4 o;
  o.x = f2bf(raw.x*scale); o.y = f2bf(raw.y*scale);
  o.z = f2bf(raw.z*scale); o.w = f2bf(raw.w*scale);
  *(ushort4*)(Zb + (size_t)row * C_TOT + c0) = o;
  *(float4*)(out_nf + (size_t)row * C_F + c0) = raw;
}

// K2: positional encoding -> normalized (x sqrt(0.05)) bf16 into Zb[:,256:288].
__global__ void k_prep_pos(const float* __restrict__ coords,
                           const float* __restrict__ hcoords,
                           u16* __restrict__ Zb) {
  int r = blockIdx.x * blockDim.x + threadIdx.x;
  if (r >= N_TOT) return;
  const float* src = (r < B_CUR) ? (coords + (size_t)r * 4)
                                 : (hcoords + (size_t)(r - B_CUR) * 4);
  float pe[32];
  float ss = 0.f;
  #pragma unroll
  for (int d = 0; d < 4; ++d) {
    float base = src[d] * 6.283185307179586f;
    #pragma unroll
    for (int f = 0; f < 4; ++f) {
      float ang = base * (float)(1 << f);
      float s = sinf(ang), co = cosf(ang);
      pe[d*8 + f]     = s;
      pe[d*8 + 4 + f] = co;
      ss += s*s + co*co;
    }
  }
  float scale = 0.22360679774997896f / fmaxf(sqrtf(ss), 1e-12f); // sqrt(0.05)
  u16* dst = Zb + (size_t)r * C_TOT + C_F;
  #pragma unroll
  for (int k = 0; k < 32; ++k) dst[k] = f2bf(pe[k] * scale);
}

// K3: S = Zb Zb^T via bf16 MFMA. 128x128 tile, BK=32, global_load_lds staging,
//     LDS-repack epilogue -> bf16 S packed into first 16KB of each output row.
#define EP_STRIDE 136   // u16; 272B rows: 16B-aligned, quads split across bank halves
__global__ __launch_bounds__(256) void k_gemm_mfma(const u16* __restrict__ Zb,
                                                   u16* __restrict__ adj16) {
  __shared__ __align__(16) u16 smem[128 * EP_STRIDE];   // 34 KB
  u16* As = smem;            // [128][32] u16 (8 KB)
  u16* Bs = smem + 4096;     // [128][32] u16 (8 KB)
  int tid  = threadIdx.x;
  int bi   = blockIdx.y, bj = blockIdx.x;
  int wave = tid >> 6, lane = tid & 63;
  int quad = lane >> 4, l16 = lane & 15;
  int m0w  = (wave >> 1) * 64;
  int n0w  = (wave & 1) * 64;
  int i0   = bi * 128, j0 = bj * 128;

  floatx4 acc[4][4];
  #pragma unroll
  for (int a = 0; a < 4; ++a)
    #pragma unroll
    for (int b = 0; b < 4; ++b) acc[a][b] = (floatx4){0.f, 0.f, 0.f, 0.f};

  int srow = wave * 16 + (lane >> 2);       // staging row within 64-row group
  int sseg = (lane & 3) * 8;                // u16 col offset (16B segment)
  for (int kt = 0; kt < C_TOT; kt += 32) {
    #pragma unroll
    for (int it = 0; it < 2; ++it) {
      int row = it * 64 + srow;
      const u16* ga = Zb + (size_t)(i0 + row) * C_TOT + kt + sseg;
      const u16* gb = Zb + (size_t)(j0 + row) * C_TOT + kt + sseg;
      GLD_LDS16(ga, As + (it * 64 + wave * 16) * 32 + lane * 8);
      GLD_LDS16(gb, Bs + (it * 64 + wave * 16) * 32 + lane * 8);
    }
    __builtin_amdgcn_s_waitcnt(0);
    __syncthreads();
    short8 af[4], bf[4];
    #pragma unroll
    for (int mi = 0; mi < 4; ++mi)
      af[mi] = *(const short8*)(&As[(m0w + mi*16 + l16) * 32 + quad * 8]);
    #pragma unroll
    for (int ni = 0; ni < 4; ++ni)
      bf[ni] = *(const short8*)(&Bs[(n0w + ni*16 + l16) * 32 + quad * 8]);
    #pragma unroll
    for (int mi = 0; mi < 4; ++mi)
      #pragma unroll
      for (int ni = 0; ni < 4; ++ni)
        acc[mi][ni] = __builtin_amdgcn_mfma_f32_16x16x32_bf16(
            af[mi], bf[ni], acc[mi][ni], 0, 0, 0);
    __syncthreads();
  }

  // Epilogue: bf16 repack through LDS, then coalesced 256B-row stores.
  float w = ((bi < 32) != (bj < 32)) ? 0.5f : 1.0f;
  #pragma unroll
  for (int mi = 0; mi < 4; ++mi) {
    #pragma unroll
    for (int ni = 0; ni < 4; ++ni) {
      int col = n0w + ni * 16 + l16;
      #pragma unroll
      for (int rg = 0; rg < 4; ++rg) {
        int row = m0w + mi * 16 + quad * 4 + rg;
        smem[row * EP_STRIDE + col] = f2bf(acc[mi][ni][rg] * w);
      }
    }
  }
  __syncthreads();
  // 256 threads, 16 lanes per row (16B each), 8 iters cover 128 rows.
  #pragma unroll
  for (int it = 0; it < 8; ++it) {
    int idx = it * 256 + tid;
    int row = idx >> 4, l = idx & 15;
    uint4 v = *(const uint4*)(&smem[row * EP_STRIDE + l * 8]);
    *(uint4*)(&adj16[(size_t)(i0 + row) * 16384 + j0 + l * 8]) = v;
  }
}

// K4: per-row top-16. bf16 row -> f32 LDS; winner-only rescan; zero f32 row.
__global__ __launch_bounds__(256) void k_topk(
    const u16* __restrict__ adj16, float* __restrict__ adj,
    int* __restrict__ topk_idx, float* __restrict__ topk_val,
    float* __restrict__ deg_out) {
  __shared__ float rowbuf[N_TOT];
  __shared__ float sv[4];
  __shared__ int   si[4];
  __shared__ float s_diag;
  int r = blockIdx.x;
  int t = threadIdx.x;
  const u16* rowp = adj16 + (size_t)r * 16384;

  #pragma unroll
  for (int it = 0; it < 4; ++it) {
    int c0 = (it * 256 + t) * 8;
    uint4 v = *(const uint4*)(rowp + c0);
    u16 e[8]; *(uint4*)e = v;
    #pragma unroll
    for (int q = 0; q < 8; ++q) rowbuf[c0 + q] = bf2f(e[q]);
  }
  __syncthreads();
  if (t == 0) { s_diag = rowbuf[r]; rowbuf[r] = INFINITY; }
  __syncthreads();
  float diagval = s_diag;

  // per-thread cached max of its 32 columns (cols kk*1024 + t*4 .. +3)
  float bv = -INFINITY; int bi = 0;
  #pragma unroll
  for (int kk = 0; kk < 8; ++kk) {
    int c0 = kk * 1024 + t * 4;
    float4 v = *(const float4*)(&rowbuf[c0]);
    if (v.x > bv) { bv = v.x; bi = c0;     }
    if (v.y > bv) { bv = v.y; bi = c0 + 1; }
    if (v.z > bv) { bv = v.z; bi = c0 + 2; }
    if (v.w > bv) { bv = v.w; bi = c0 + 3; }
  }

  float degacc = 0.f;
  for (int it = 0; it < KSEL; ++it) {
    float rv = bv; int ri = bi;
    #pragma unroll
    for (int m = 32; m; m >>= 1) {
      float ov = __shfl_xor(rv, m, 64);
      int   oi = __shfl_xor(ri, m, 64);
      if (ov > rv || (ov == rv && oi < ri)) { rv = ov; ri = oi; }
    }
    int lane = t & 63, wvid = t >> 6;
    if (lane == 0) { sv[wvid] = rv; si[wvid] = ri; }
    __syncthreads();
    float wv_ = sv[0]; int wi_ = si[0];
    #pragma unroll
    for (int q = 1; q < 4; ++q) {
      float ov = sv[q]; int oi = si[q];
      if (ov > wv_ || (ov == wv_ && oi < wi_)) { wv_ = ov; wi_ = oi; }
    }
    if (t == 0) {
      float val = (wi_ == r) ? diagval : wv_;
      topk_idx[r*KSEL + it] = wi_;
      topk_val[r*KSEL + it] = val;
      degacc += val;
    }
    if (t == ((wi_ >> 2) & 255)) {     // owner: mark taken, rescan own 32 cols
      rowbuf[wi_] = -INFINITY;
      bv = -INFINITY; bi = wi_;
      #pragma unroll
      for (int kk = 0; kk < 8; ++kk) {
        int c0 = kk * 1024 + t * 4;
        float4 v = *(const float4*)(&rowbuf[c0]);
        if (v.x > bv) { bv = v.x; bi = c0;     }
        if (v.y > bv) { bv = v.y; bi = c0 + 1; }
        if (v.z > bv) { bv = v.z; bi = c0 + 2; }
        if (v.w > bv) { bv = v.w; bi = c0 + 3; }
      }
    }
    __syncthreads();
  }
  if (t == 0) deg_out[r] = degacc;

  // zero the full f32 output row (kept entries rewritten by k_scale)
  float* oro = adj + (size_t)r * N_TOT;
  const float4 z4 = make_float4(0.f, 0.f, 0.f, 0.f);
  #pragma unroll
  for (int kk = 0; kk < 8; ++kk)
    *(float4*)(oro + kk * 1024 + t * 4) = z4;
}

// K5: write kept entries scaled by d^-1/2 on both sides.
__global__ void k_scale(float* __restrict__ adj, const int* __restrict__ topk_idx,
                        const float* __restrict__ topk_val,
                        const float* __restrict__ deg) {
  int g = blockIdx.x * blockDim.x + threadIdx.x;
  if (g >= N_TOT * KSEL) return;
  int r = g >> 4, m = g & 15;
  int j = topk_idx[r*KSEL + m];
  if (j < 0) j = 0; if (j >= N_TOT) j = N_TOT - 1;  // insurance
  float v = topk_val[r*KSEL + m];
  float di = 1.0f / sqrtf(fmaxf(deg[r], 1e-12f));
  float dj = 1.0f / sqrtf(fmaxf(deg[j], 1e-12f));
  adj[(size_t)r * N_TOT + j] = v * di * dj;
}

extern "C" void kernel_launch(void* const* d_in, const int* in_sizes, int n_in,
                              void* d_out, int out_size, void* d_ws, size_t ws_size,
                              hipStream_t stream) {
  const float* feats   = (const float*)d_in[0];
  const float* coords  = (const float*)d_in[1];
  const float* hfeats  = (const float*)d_in[2];
  const float* hcoords = (const float*)d_in[3];
  float* out    = (float*)d_out;
  float* adj    = out;                               // [8192, 8192] f32
  u16*   adj16  = (u16*)out;                         // bf16 S packed per-row
  float* out_nf = out + (size_t)N_TOT * N_TOT;       // [8192, 256]  f32

  char* ws    = (char*)d_ws;
  u16*  Zb    = (u16*)ws;                            // 8192*288 bf16 (4.7 MB)
  size_t zb   = (size_t)N_TOT * C_TOT * sizeof(u16);
  zb = (zb + 255) & ~(size_t)255;
  int*   t_idx = (int*)(ws + zb);
  float* t_val = (float*)(ws + zb + (size_t)N_TOT*KSEL*sizeof(int));
  float* deg   = (float*)(ws + zb + (size_t)N_TOT*KSEL*(sizeof(int)+sizeof(float)));

  hipLaunchKernelGGL(k_prep_feats, dim3(N_TOT/4), dim3(256), 0, stream,
                     feats, hfeats, Zb, out_nf);
  hipLaunchKernelGGL(k_prep_pos, dim3(N_TOT/256), dim3(256), 0, stream,
                     coords, hcoords, Zb);
  hipLaunchKernelGGL(k_gemm_mfma, dim3(64, 64), dim3(256), 0, stream, Zb, adj16);
  hipLaunchKernelGGL(k_topk, dim3(N_TOT), dim3(256), 0, stream,
                     adj16, adj, t_idx, t_val, deg);
  hipLaunchKernelGGL(k_scale, dim3((N_TOT*KSEL + 255)/256), dim3(256), 0, stream,
                     adj, t_idx, t_val, deg);
}

// Round 7
// 436.941 us; speedup vs baseline: 3.8431x; 1.1680x over previous
//
#include <hip/hip_runtime.h>
#include <math.h>

#define B_CUR 4096
#define N_TOT 8192
#define C_F   256
#define C_TOT 288
#define KSEL  16

typedef unsigned short u16;
typedef __attribute__((ext_vector_type(8))) short short8;
typedef __attribute__((ext_vector_type(4))) float floatx4;

__device__ inline float bf2f(u16 v) {
  union { unsigned int u; float f; } x; x.u = ((unsigned int)v) << 16; return x.f;
}
__device__ inline u16 f2bf(float f) {
  union { float f; unsigned int u; } x; x.f = f;
  unsigned int u = x.u;
  u += ((u >> 16) & 1u) + 0x7FFFu;   // RNE
  return (u16)(u >> 16);
}

#define GLD_LDS16(g, l) __builtin_amdgcn_global_load_lds(                      \
    (const __attribute__((address_space(1))) unsigned int*)(g),                \
    (__attribute__((address_space(3))) unsigned int*)(l), 16, 0, 0)

// K1: normalize feature rows (x sqrt(0.95)) -> bf16 Zb; copy raw feats to out_nf.
__global__ __launch_bounds__(256) void k_prep_feats(
    const float* __restrict__ feats, const float* __restrict__ hfeats,
    u16* __restrict__ Zb, float* __restrict__ out_nf) {
  int wave = threadIdx.x >> 6;
  int lane = threadIdx.x & 63;
  int row  = blockIdx.x * 4 + wave;
  const float* src = (row < B_CUR) ? (feats + (size_t)row * C_F)
                                   : (hfeats + (size_t)(row - B_CUR) * C_F);
  int c0 = lane * 4;
  float4 raw = *(const float4*)(src + c0);
  float ss = raw.x*raw.x + raw.y*raw.y + raw.z*raw.z + raw.w*raw.w;
  #pragma unroll
  for (int m = 32; m; m >>= 1) ss += __shfl_xor(ss, m, 64);
  float scale = 0.97467943448089633f / fmaxf(sqrtf(ss), 1e-12f);   // sqrt(0.95)
  ushort4 o;
  o.x = f2bf(raw.x*scale); o.y = f2bf(raw.y*scale);
  o.z = f2bf(raw.z*scale); o.w = f2bf(raw.w*scale);
  *(ushort4*)(Zb + (size_t)row * C_TOT + c0) = o;
  *(float4*)(out_nf + (size_t)row * C_F + c0) = raw;
}

// K2: positional encoding -> normalized (x sqrt(0.05)) bf16 into Zb[:,256:288].
__global__ void k_prep_pos(const float* __restrict__ coords,
                           const float* __restrict__ hcoords,
                           u16* __restrict__ Zb) {
  int r = blockIdx.x * blockDim.x + threadIdx.x;
  if (r >= N_TOT) return;
  const float* src = (r < B_CUR) ? (coords + (size_t)r * 4)
                                 : (hcoords + (size_t)(r - B_CUR) * 4);
  float pe[32];
  float ss = 0.f;
  #pragma unroll
  for (int d = 0; d < 4; ++d) {
    float base = src[d] * 6.283185307179586f;
    #pragma unroll
    for (int f = 0; f < 4; ++f) {
      float ang = base * (float)(1 << f);
      float s = sinf(ang), co = cosf(ang);
      pe[d*8 + f]     = s;
      pe[d*8 + 4 + f] = co;
      ss += s*s + co*co;
    }
  }
  float scale = 0.22360679774997896f / fmaxf(sqrtf(ss), 1e-12f); // sqrt(0.05)
  u16* dst = Zb + (size_t)r * C_TOT + C_F;
  #pragma unroll
  for (int k = 0; k < 32; ++k) dst[k] = f2bf(pe[k] * scale);
}

// K3: S = Zb Zb^T via bf16 MFMA. 128x128 tile, BK=32, global_load_lds staging,
//     LDS-repack epilogue -> bf16 S packed into first 16KB of each output row.
#define EP_STRIDE 136
__global__ __launch_bounds__(256) void k_gemm_mfma(const u16* __restrict__ Zb,
                                                   u16* __restrict__ adj16) {
  __shared__ __align__(16) u16 smem[128 * EP_STRIDE];   // 34 KB
  u16* As = smem;            // [128][32] u16 (8 KB)
  u16* Bs = smem + 4096;     // [128][32] u16 (8 KB)
  int tid  = threadIdx.x;
  int bi   = blockIdx.y, bj = blockIdx.x;
  int wave = tid >> 6, lane = tid & 63;
  int quad = lane >> 4, l16 = lane & 15;
  int m0w  = (wave >> 1) * 64;
  int n0w  = (wave & 1) * 64;
  int i0   = bi * 128, j0 = bj * 128;

  floatx4 acc[4][4];
  #pragma unroll
  for (int a = 0; a < 4; ++a)
    #pragma unroll
    for (int b = 0; b < 4; ++b) acc[a][b] = (floatx4){0.f, 0.f, 0.f, 0.f};

  int srow = wave * 16 + (lane >> 2);
  int sseg = (lane & 3) * 8;
  for (int kt = 0; kt < C_TOT; kt += 32) {
    #pragma unroll
    for (int it = 0; it < 2; ++it) {
      int row = it * 64 + srow;
      const u16* ga = Zb + (size_t)(i0 + row) * C_TOT + kt + sseg;
      const u16* gb = Zb + (size_t)(j0 + row) * C_TOT + kt + sseg;
      GLD_LDS16(ga, As + (it * 64 + wave * 16) * 32 + lane * 8);
      GLD_LDS16(gb, Bs + (it * 64 + wave * 16) * 32 + lane * 8);
    }
    __builtin_amdgcn_s_waitcnt(0);
    __syncthreads();
    short8 af[4], bf[4];
    #pragma unroll
    for (int mi = 0; mi < 4; ++mi)
      af[mi] = *(const short8*)(&As[(m0w + mi*16 + l16) * 32 + quad * 8]);
    #pragma unroll
    for (int ni = 0; ni < 4; ++ni)
      bf[ni] = *(const short8*)(&Bs[(n0w + ni*16 + l16) * 32 + quad * 8]);
    #pragma unroll
    for (int mi = 0; mi < 4; ++mi)
      #pragma unroll
      for (int ni = 0; ni < 4; ++ni)
        acc[mi][ni] = __builtin_amdgcn_mfma_f32_16x16x32_bf16(
            af[mi], bf[ni], acc[mi][ni], 0, 0, 0);
    __syncthreads();
  }

  float w = ((bi < 32) != (bj < 32)) ? 0.5f : 1.0f;
  #pragma unroll
  for (int mi = 0; mi < 4; ++mi) {
    #pragma unroll
    for (int ni = 0; ni < 4; ++ni) {
      int col = n0w + ni * 16 + l16;
      #pragma unroll
      for (int rg = 0; rg < 4; ++rg) {
        int row = m0w + mi * 16 + quad * 4 + rg;
        smem[row * EP_STRIDE + col] = f2bf(acc[mi][ni][rg] * w);
      }
    }
  }
  __syncthreads();
  #pragma unroll
  for (int it = 0; it < 8; ++it) {
    int idx = it * 256 + tid;
    int row = idx >> 4, l = idx & 15;
    uint4 v = *(const uint4*)(&smem[row * EP_STRIDE + l * 8]);
    *(uint4*)(&adj16[(size_t)(i0 + row) * 16384 + j0 + l * 8]) = v;
  }
}

// K4: per-row top-16 via packed sortable u32 keys; wave-local top-16 (no barriers),
//     single cross-wave merge. No zero-write here (moved to k_scale_zero).
#define TOP2(x) { unsigned int xv_ = (x); \
  if (xv_ > m1) { m2 = m1; m1 = xv_; } else if (xv_ > m2) { m2 = xv_; } }

__global__ __launch_bounds__(256) void k_topk(
    const u16* __restrict__ adj16,
    int* __restrict__ topk_idx, float* __restrict__ topk_val,
    float* __restrict__ deg_out) {
  __shared__ unsigned int keys[N_TOT];   // 32 KB
  __shared__ unsigned int cand[64];
  __shared__ float s_diag;
  int r = blockIdx.x;
  int t = threadIdx.x;
  int wave = t >> 6, lane = t & 63;
  const u16* rowp = adj16 + (size_t)r * 16384;

  // stage packed keys: high16 = sortable bf16, low13 = 8191-col (lowest col wins ties)
  #pragma unroll
  for (int it = 0; it < 4; ++it) {
    int c0 = it * 2048 + t * 8;
    uint4 v = *(const uint4*)(rowp + c0);
    u16 e[8]; *(uint4*)e = v;
    unsigned int kk[8];
    #pragma unroll
    for (int q = 0; q < 8; ++q) {
      unsigned int b = e[q];
      unsigned int s16 = (b & 0x8000u) ? (b ^ 0xFFFFu) : (b | 0x8000u);
      kk[q] = (s16 << 16) | (unsigned int)(8191 - (c0 + q));
    }
    *(uint4*)(&keys[c0])     = *(uint4*)(&kk[0]);
    *(uint4*)(&keys[c0 + 4]) = *(uint4*)(&kk[4]);
  }
  __syncthreads();
  if (t == 0) {
    s_diag = bf2f(rowp[r]);
    keys[r] = 0xFFFF0000u | (unsigned int)(8191 - r);  // forced max, decodes to col r
  }
  __syncthreads();
  float diagval = s_diag;

  // per-lane top-2 over its 32 cols: wave's segment [wave*2048, +2048),
  // lane owns cols wave*2048 + j*256 + lane*4 (contiguous uint4 per j -> conflict-free)
  unsigned int m1 = 0, m2 = 0;
  int base = wave * 2048 + lane * 4;
  #pragma unroll
  for (int j = 0; j < 8; ++j) {
    uint4 v = *(const uint4*)(&keys[base + j * 256]);
    TOP2(v.x) TOP2(v.y) TOP2(v.z) TOP2(v.w)
  }

  // wave-local top-16, zero barriers
  for (int it = 0; it < KSEL; ++it) {
    unsigned int wmax = m1;
    #pragma unroll
    for (int s = 32; s; s >>= 1) {
      unsigned int o = (unsigned int)__shfl_xor((int)wmax, s, 64);
      wmax = (o > wmax) ? o : wmax;
    }
    if (lane == it) cand[wave * 16 + it] = wmax;
    if (m1 == wmax) {                      // unique owner (keys unique)
      int col = 8191 - (int)(wmax & 0x1FFFu);
      keys[col] = 0;
      if (m2 != 0) { m1 = m2; m2 = 0; }
      else {                               // rebuild top-2 from LDS (taken are 0)
        m1 = 0; m2 = 0;
        #pragma unroll
        for (int j = 0; j < 8; ++j) {
          uint4 v = *(const uint4*)(&keys[base + j * 256]);
          TOP2(v.x) TOP2(v.y) TOP2(v.z) TOP2(v.w)
        }
      }
    }
  }
  __syncthreads();

  // wave 0 merges 64 candidates -> global top-16, writes outputs
  if (wave == 0) {
    unsigned int c = cand[lane];
    unsigned int myWin = 0;
    for (int it = 0; it < KSEL; ++it) {
      unsigned int wmax = c;
      #pragma unroll
      for (int s = 32; s; s >>= 1) {
        unsigned int o = (unsigned int)__shfl_xor((int)wmax, s, 64);
        wmax = (o > wmax) ? o : wmax;
      }
      if (c == wmax) c = 0;
      if (lane == it) myWin = wmax;
    }
    float val = 0.f;
    int col = 0;
    if (lane < KSEL) {
      unsigned int p = myWin;
      col = 8191 - (int)(p & 0x1FFFu);
      unsigned int k16 = p >> 16;
      unsigned int b = (k16 & 0x8000u) ? (k16 ^ 0x8000u) : ((~k16) & 0xFFFFu);
      val = (col == r) ? diagval : bf2f((u16)b);
      topk_idx[r * KSEL + lane] = col;
      topk_val[r * KSEL + lane] = val;
    }
    float s = (lane < KSEL) ? val : 0.f;
    #pragma unroll
    for (int m = 8; m; m >>= 1) s += __shfl_xor(s, m, 64);
    if (lane == 0) deg_out[r] = s;
  }
}

// K5: per row -- stream zeros over the f32 row, then write the 16 scaled entries.
__global__ __launch_bounds__(256) void k_scale_zero(
    float* __restrict__ adj, const int* __restrict__ topk_idx,
    const float* __restrict__ topk_val, const float* __restrict__ deg) {
  int r = blockIdx.x, t = threadIdx.x;
  float* row = adj + (size_t)r * N_TOT;
  const float4 z4 = make_float4(0.f, 0.f, 0.f, 0.f);
  #pragma unroll
  for (int kk = 0; kk < 8; ++kk)
    *(float4*)(row + kk * 1024 + t * 4) = z4;
  __syncthreads();   // order zero-stores before scatter-stores (block-level)
  if (t < KSEL) {
    int j = topk_idx[r * KSEL + t];
    if (j < 0) j = 0; if (j >= N_TOT) j = N_TOT - 1;   // insurance
    float v = topk_val[r * KSEL + t];
    float di = 1.0f / sqrtf(fmaxf(deg[r], 1e-12f));
    float dj = 1.0f / sqrtf(fmaxf(deg[j], 1e-12f));
    row[j] = v * di * dj;
  }
}

extern "C" void kernel_launch(void* const* d_in, const int* in_sizes, int n_in,
                              void* d_out, int out_size, void* d_ws, size_t ws_size,
                              hipStream_t stream) {
  const float* feats   = (const float*)d_in[0];
  const float* coords  = (const float*)d_in[1];
  const float* hfeats  = (const float*)d_in[2];
  const float* hcoords = (const float*)d_in[3];
  float* out    = (float*)d_out;
  float* adj    = out;                               // [8192, 8192] f32
  u16*   adj16  = (u16*)out;                         // bf16 S packed per-row
  float* out_nf = out + (size_t)N_TOT * N_TOT;       // [8192, 256]  f32

  char* ws    = (char*)d_ws;
  u16*  Zb    = (u16*)ws;                            // 8192*288 bf16 (4.7 MB)
  size_t zb   = (size_t)N_TOT * C_TOT * sizeof(u16);
  zb = (zb + 255) & ~(size_t)255;
  int*   t_idx = (int*)(ws + zb);
  float* t_val = (float*)(ws + zb + (size_t)N_TOT*KSEL*sizeof(int));
  float* deg   = (float*)(ws + zb + (size_t)N_TOT*KSEL*(sizeof(int)+sizeof(float)));

  hipLaunchKernelGGL(k_prep_feats, dim3(N_TOT/4), dim3(256), 0, stream,
                     feats, hfeats, Zb, out_nf);
  hipLaunchKernelGGL(k_prep_pos, dim3(N_TOT/256), dim3(256), 0, stream,
                     coords, hcoords, Zb);
  hipLaunchKernelGGL(k_gemm_mfma, dim3(64, 64), dim3(256), 0, stream, Zb, adj16);
  hipLaunchKernelGGL(k_topk, dim3(N_TOT), dim3(256), 0, stream,
                     adj16, t_idx, t_val, deg);
  hipLaunchKernelGGL(k_scale_zero, dim3(N_TOT), dim3(256), 0, stream,
                     adj, t_idx, t_val, deg);
}

// Round 9
// 431.804 us; speedup vs baseline: 3.8888x; 1.0119x over previous
//
#include <hip/hip_runtime.h>
#include <math.h>

#define B_CUR 4096
#define N_TOT 8192
#define C_F   256
#define C_TOT 288
#define KSEL  16
#define NTILE 64    // 8192 / 128

typedef unsigned short u16;
typedef __attribute__((ext_vector_type(8))) short short8;
typedef __attribute__((ext_vector_type(4))) float floatx4;

__device__ inline float bf2f(u16 v) {
  union { unsigned int u; float f; } x; x.u = ((unsigned int)v) << 16; return x.f;
}
__device__ inline u16 f2bf(float f) {
  union { float f; unsigned int u; } x; x.f = f;
  unsigned int u = x.u;
  u += ((u >> 16) & 1u) + 0x7FFFu;   // RNE
  return (u16)(u >> 16);
}

#define GLD_LDS16(g, l) __builtin_amdgcn_global_load_lds(                      \
    (const __attribute__((address_space(1))) unsigned int*)(g),                \
    (__attribute__((address_space(3))) unsigned int*)(l), 16, 0, 0)

// K1: normalize feature rows (x sqrt(0.95)) -> bf16 Zb; copy raw feats to out_nf.
__global__ __launch_bounds__(256) void k_prep_feats(
    const float* __restrict__ feats, const float* __restrict__ hfeats,
    u16* __restrict__ Zb, float* __restrict__ out_nf) {
  int wave = threadIdx.x >> 6;
  int lane = threadIdx.x & 63;
  int row  = blockIdx.x * 4 + wave;
  const float* src = (row < B_CUR) ? (feats + (size_t)row * C_F)
                                   : (hfeats + (size_t)(row - B_CUR) * C_F);
  int c0 = lane * 4;
  float4 raw = *(const float4*)(src + c0);
  float ss = raw.x*raw.x + raw.y*raw.y + raw.z*raw.z + raw.w*raw.w;
  #pragma unroll
  for (int m = 32; m; m >>= 1) ss += __shfl_xor(ss, m, 64);
  float scale = 0.97467943448089633f / fmaxf(sqrtf(ss), 1e-12f);   // sqrt(0.95)
  ushort4 o;
  o.x = f2bf(raw.x*scale); o.y = f2bf(raw.y*scale);
  o.z = f2bf(raw.z*scale); o.w = f2bf(raw.w*scale);
  *(ushort4*)(Zb + (size_t)row * C_TOT + c0) = o;
  *(float4*)(out_nf + (size_t)row * C_F + c0) = raw;
}

// K2: positional encoding -> normalized (x sqrt(0.05)) bf16 into Zb[:,256:288].
__global__ void k_prep_pos(const float* __restrict__ coords,
                           const float* __restrict__ hcoords,
                           u16* __restrict__ Zb) {
  int r = blockIdx.x * blockDim.x + threadIdx.x;
  if (r >= N_TOT) return;
  const float* src = (r < B_CUR) ? (coords + (size_t)r * 4)
                                 : (hcoords + (size_t)(r - B_CUR) * 4);
  float pe[32];
  float ss = 0.f;
  #pragma unroll
  for (int d = 0; d < 4; ++d) {
    float base = src[d] * 6.283185307179586f;
    #pragma unroll
    for (int f = 0; f < 4; ++f) {
      float ang = base * (float)(1 << f);
      float s = sinf(ang), co = cosf(ang);
      pe[d*8 + f]     = s;
      pe[d*8 + 4 + f] = co;
      ss += s*s + co*co;
    }
  }
  float scale = 0.22360679774997896f / fmaxf(sqrtf(ss), 1e-12f); // sqrt(0.05)
  u16* dst = Zb + (size_t)r * C_TOT + C_F;
  #pragma unroll
  for (int k = 0; k < 32; ++k) dst[k] = f2bf(pe[k] * scale);
}

// K3: S = Zb Zb^T, symmetric: only upper-triangle 128x128 tiles computed
//     (2080 blocks); off-diag tiles mirrored via a 2nd transposed repack.
//     BK=96 single-buffered (3 k-iters, 3 barrier pairs vs 9).
#define EP_STRIDE 136
__global__ __launch_bounds__(256) void k_gemm_mfma(const u16* __restrict__ Zb,
                                                   u16* __restrict__ adj16) {
  __shared__ __align__(16) u16 smem[2 * 128 * 96];     // 49152 B
  u16* As = smem;               // [128][96] u16
  u16* Bs = smem + 128 * 96;    // [128][96] u16
  int tid  = threadIdx.x;

  // decode linear block id -> upper-triangle (bi <= bj)
  int t = blockIdx.x;
  int bi = (int)floorf(((2.0f*NTILE + 1.0f) -
            sqrtf((float)((2*NTILE+1)*(2*NTILE+1)) - 8.0f*(float)t)) * 0.5f);
  if (bi < 0) bi = 0; if (bi > NTILE-1) bi = NTILE-1;
  while (bi > 0 && t < bi*NTILE - bi*(bi-1)/2) --bi;
  while (bi < NTILE-1 && t >= (bi+1)*NTILE - (bi+1)*bi/2) ++bi;
  int bj = bi + (t - (bi*NTILE - bi*(bi-1)/2));

  int wave = tid >> 6, lane = tid & 63;
  int quad = lane >> 4, l16 = lane & 15;
  int m0w  = (wave >> 1) * 64;
  int n0w  = (wave & 1) * 64;
  int i0   = bi * 128, j0 = bj * 128;

  floatx4 acc[4][4];
  #pragma unroll
  for (int a = 0; a < 4; ++a)
    #pragma unroll
    for (int b = 0; b < 4; ++b) acc[a][b] = (floatx4){0.f, 0.f, 0.f, 0.f};

  for (int kt = 0; kt < C_TOT; kt += 96) {
    // stage A,B chunks: 128 rows x 96 cols = 1536 16B-segments each, 6/thread
    #pragma unroll
    for (int it = 0; it < 6; ++it) {
      int s   = it * 256 + tid;       // 0..1535
      int row = s / 12, seg = s % 12; // 12 segments of 16B per 96-col row
      const u16* ga = Zb + (size_t)(i0 + row) * C_TOT + kt + seg * 8;
      const u16* gb = Zb + (size_t)(j0 + row) * C_TOT + kt + seg * 8;
      GLD_LDS16(ga, As + s * 8);
      GLD_LDS16(gb, Bs + s * 8);
    }
    __builtin_amdgcn_s_waitcnt(0);
    __syncthreads();
    #pragma unroll
    for (int ks = 0; ks < 3; ++ks) {
      short8 af[4], bf[4];
      #pragma unroll
      for (int mi = 0; mi < 4; ++mi)
        af[mi] = *(const short8*)(&As[(m0w + mi*16 + l16) * 96 + ks*32 + quad*8]);
      #pragma unroll
      for (int ni = 0; ni < 4; ++ni)
        bf[ni] = *(const short8*)(&Bs[(n0w + ni*16 + l16) * 96 + ks*32 + quad*8]);
      #pragma unroll
      for (int mi = 0; mi < 4; ++mi)
        #pragma unroll
        for (int ni = 0; ni < 4; ++ni)
          acc[mi][ni] = __builtin_amdgcn_mfma_f32_16x16x32_bf16(
              af[mi], bf[ni], acc[mi][ni], 0, 0, 0);
    }
    __syncthreads();
  }

  float w = ((bi < 32) != (bj < 32)) ? 0.5f : 1.0f;

  // pass 1: normal orientation -> tile (bi, bj)
  #pragma unroll
  for (int mi = 0; mi < 4; ++mi) {
    #pragma unroll
    for (int ni = 0; ni < 4; ++ni) {
      int col = n0w + ni * 16 + l16;
      #pragma unroll
      for (int rg = 0; rg < 4; ++rg) {
        int row = m0w + mi * 16 + quad * 4 + rg;
        smem[row * EP_STRIDE + col] = f2bf(acc[mi][ni][rg] * w);
      }
    }
  }
  __syncthreads();
  #pragma unroll
  for (int it = 0; it < 8; ++it) {
    int idx = it * 256 + tid;
    int row = idx >> 4, l = idx & 15;
    uint4 v = *(const uint4*)(&smem[row * EP_STRIDE + l * 8]);
    *(uint4*)(&adj16[(size_t)(i0 + row) * 16384 + j0 + l * 8]) = v;
  }

  if (bi != bj) {
    __syncthreads();   // stores' LDS reads done before overwrite
    // pass 2: transposed -> tile (bj, bi)
    #pragma unroll
    for (int mi = 0; mi < 4; ++mi) {
      #pragma unroll
      for (int ni = 0; ni < 4; ++ni) {
        int col = n0w + ni * 16 + l16;
        #pragma unroll
        for (int rg = 0; rg < 4; ++rg) {
          int row = m0w + mi * 16 + quad * 4 + rg;
          smem[col * EP_STRIDE + row] = f2bf(acc[mi][ni][rg] * w);
        }
      }
    }
    __syncthreads();
    #pragma unroll
    for (int it = 0; it < 8; ++it) {
      int idx = it * 256 + tid;
      int row = idx >> 4, l = idx & 15;
      uint4 v = *(const uint4*)(&smem[row * EP_STRIDE + l * 8]);
      *(uint4*)(&adj16[(size_t)(j0 + row) * 16384 + i0 + l * 8]) = v;
    }
  }
}

// K4: per-row top-16 via packed sortable u32 keys; wave-local top-16 (no barriers),
//     single cross-wave merge. No zero-write here (moved to k_scale_zero).
#define TOP2(x) { unsigned int xv_ = (x); \
  if (xv_ > m1) { m2 = m1; m1 = xv_; } else if (xv_ > m2) { m2 = xv_; } }

__global__ __launch_bounds__(256) void k_topk(
    const u16* __restrict__ adj16,
    int* __restrict__ topk_idx, float* __restrict__ topk_val,
    float* __restrict__ deg_out) {
  __shared__ unsigned int keys[N_TOT];   // 32 KB
  __shared__ unsigned int cand[64];
  __shared__ float s_diag;
  int r = blockIdx.x;
  int t = threadIdx.x;
  int wave = t >> 6, lane = t & 63;
  const u16* rowp = adj16 + (size_t)r * 16384;

  #pragma unroll
  for (int it = 0; it < 4; ++it) {
    int c0 = it * 2048 + t * 8;
    uint4 v = *(const uint4*)(rowp + c0);
    u16 e[8]; *(uint4*)e = v;
    unsigned int kk[8];
    #pragma unroll
    for (int q = 0; q < 8; ++q) {
      unsigned int b = e[q];
      unsigned int s16 = (b & 0x8000u) ? (b ^ 0xFFFFu) : (b | 0x8000u);
      kk[q] = (s16 << 16) | (unsigned int)(8191 - (c0 + q));
    }
    *(uint4*)(&keys[c0])     = *(uint4*)(&kk[0]);
    *(uint4*)(&keys[c0 + 4]) = *(uint4*)(&kk[4]);
  }
  __syncthreads();
  if (t == 0) {
    s_diag = bf2f(rowp[r]);
    keys[r] = 0xFFFF0000u | (unsigned int)(8191 - r);
  }
  __syncthreads();
  float diagval = s_diag;

  unsigned int m1 = 0, m2 = 0;
  int base = wave * 2048 + lane * 4;
  #pragma unroll
  for (int j = 0; j < 8; ++j) {
    uint4 v = *(const uint4*)(&keys[base + j * 256]);
    TOP2(v.x) TOP2(v.y) TOP2(v.z) TOP2(v.w)
  }

  for (int it = 0; it < KSEL; ++it) {
    unsigned int wmax = m1;
    #pragma unroll
    for (int s = 32; s; s >>= 1) {
      unsigned int o = (unsigned int)__shfl_xor((int)wmax, s, 64);
      wmax = (o > wmax) ? o : wmax;
    }
    if (lane == it) cand[wave * 16 + it] = wmax;
    if (m1 == wmax) {
      int col = 8191 - (int)(wmax & 0x1FFFu);
      keys[col] = 0;
      if (m2 != 0) { m1 = m2; m2 = 0; }
      else {
        m1 = 0; m2 = 0;
        #pragma unroll
        for (int j = 0; j < 8; ++j) {
          uint4 v = *(const uint4*)(&keys[base + j * 256]);
          TOP2(v.x) TOP2(v.y) TOP2(v.z) TOP2(v.w)
        }
      }
    }
  }
  __syncthreads();

  if (wave == 0) {
    unsigned int c = cand[lane];
    unsigned int myWin = 0;
    for (int it = 0; it < KSEL; ++it) {
      unsigned int wmax = c;
      #pragma unroll
      for (int s = 32; s; s >>= 1) {
        unsigned int o = (unsigned int)__shfl_xor((int)wmax, s, 64);
        wmax = (o > wmax) ? o : wmax;
      }
      if (c == wmax) c = 0;
      if (lane == it) myWin = wmax;
    }
    float val = 0.f;
    int col = 0;
    if (lane < KSEL) {
      unsigned int p = myWin;
      col = 8191 - (int)(p & 0x1FFFu);
      unsigned int k16 = p >> 16;
      unsigned int b = (k16 & 0x8000u) ? (k16 ^ 0x8000u) : ((~k16) & 0xFFFFu);
      val = (col == r) ? diagval : bf2f((u16)b);
      topk_idx[r * KSEL + lane] = col;
      topk_val[r * KSEL + lane] = val;
    }
    float s = (lane < KSEL) ? val : 0.f;
    #pragma unroll
    for (int m = 8; m; m >>= 1) s += __shfl_xor(s, m, 64);
    if (lane == 0) deg_out[r] = s;
  }
}

// K5: per row -- stream zeros over the f32 row, then write the 16 scaled entries.
__global__ __launch_bounds__(256) void k_scale_zero(
    float* __restrict__ adj, const int* __restrict__ topk_idx,
    const float* __restrict__ topk_val, const float* __restrict__ deg) {
  int r = blockIdx.x, t = threadIdx.x;
  float* row = adj + (size_t)r * N_TOT;
  const float4 z4 = make_float4(0.f, 0.f, 0.f, 0.f);
  #pragma unroll
  for (int kk = 0; kk < 8; ++kk)
    *(float4*)(row + kk * 1024 + t * 4) = z4;
  __syncthreads();
  if (t < KSEL) {
    int j = topk_idx[r * KSEL + t];
    if (j < 0) j = 0; if (j >= N_TOT) j = N_TOT - 1;
    float v = topk_val[r * KSEL + t];
    float di = 1.0f / sqrtf(fmaxf(deg[r], 1e-12f));
    float dj = 1.0f / sqrtf(fmaxf(deg[j], 1e-12f));
    row[j] = v * di * dj;
  }
}

extern "C" void kernel_launch(void* const* d_in, const int* in_sizes, int n_in,
                              void* d_out, int out_size, void* d_ws, size_t ws_size,
                              hipStream_t stream) {
  const float* feats   = (const float*)d_in[0];
  const float* coords  = (const float*)d_in[1];
  const float* hfeats  = (const float*)d_in[2];
  const float* hcoords = (const float*)d_in[3];
  float* out    = (float*)d_out;
  float* adj    = out;                               // [8192, 8192] f32
  u16*   adj16  = (u16*)out;                         // bf16 S packed per-row
  float* out_nf = out + (size_t)N_TOT * N_TOT;       // [8192, 256]  f32

  char* ws    = (char*)d_ws;
  u16*  Zb    = (u16*)ws;
  size_t zb   = (size_t)N_TOT * C_TOT * sizeof(u16);
  zb = (zb + 255) & ~(size_t)255;
  int*   t_idx = (int*)(ws + zb);
  float* t_val = (float*)(ws + zb + (size_t)N_TOT*KSEL*sizeof(int));
  float* deg   = (float*)(ws + zb + (size_t)N_TOT*KSEL*(sizeof(int)+sizeof(float)));

  hipLaunchKernelGGL(k_prep_feats, dim3(N_TOT/4), dim3(256), 0, stream,
                     feats, hfeats, Zb, out_nf);
  hipLaunchKernelGGL(k_prep_pos, dim3(N_TOT/256), dim3(256), 0, stream,
                     coords, hcoords, Zb);
  hipLaunchKernelGGL(k_gemm_mfma, dim3(NTILE*(NTILE+1)/2), dim3(256), 0, stream,
                     Zb, adj16);
  hipLaunchKernelGGL(k_topk, dim3(N_TOT), dim3(256), 0, stream,
                     adj16, t_idx, t_val, deg);
  hipLaunchKernelGGL(k_scale_zero, dim3(N_TOT), dim3(256), 0, stream,
                     adj, t_idx, t_val, deg);
}

// Round 10
// 400.855 us; speedup vs baseline: 4.1890x; 1.0772x over previous
//
#include <hip/hip_runtime.h>
#include <math.h>

#define B_CUR 4096
#define N_TOT 8192
#define C_F   256
#define C_TOT 288
#define KSEL  16
#define NTILE 64    // 8192 / 128

typedef unsigned short u16;
typedef __attribute__((ext_vector_type(8))) short short8;
typedef __attribute__((ext_vector_type(4))) float floatx4;

__device__ inline float bf2f(u16 v) {
  union { unsigned int u; float f; } x; x.u = ((unsigned int)v) << 16; return x.f;
}
__device__ inline u16 f2bf(float f) {
  union { float f; unsigned int u; } x; x.f = f;
  unsigned int u = x.u;
  u += ((u >> 16) & 1u) + 0x7FFFu;   // RNE
  return (u16)(u >> 16);
}

#define GLD_LDS16(g, l) __builtin_amdgcn_global_load_lds(                      \
    (const __attribute__((address_space(1))) unsigned int*)(g),                \
    (__attribute__((address_space(3))) unsigned int*)(l), 16, 0, 0)

// K1 (fused): per wave = one row. Feature normalize (64 lanes) + PE (32 lanes).
__global__ __launch_bounds__(256) void k_prep(
    const float* __restrict__ feats, const float* __restrict__ hfeats,
    const float* __restrict__ coords, const float* __restrict__ hcoords,
    u16* __restrict__ Zb, float* __restrict__ out_nf) {
  int wave = threadIdx.x >> 6;
  int lane = threadIdx.x & 63;
  int row  = blockIdx.x * 4 + wave;
  const float* src = (row < B_CUR) ? (feats + (size_t)row * C_F)
                                   : (hfeats + (size_t)(row - B_CUR) * C_F);
  int c0 = lane * 4;
  float4 raw = *(const float4*)(src + c0);
  float ss = raw.x*raw.x + raw.y*raw.y + raw.z*raw.z + raw.w*raw.w;
  #pragma unroll
  for (int m = 32; m; m >>= 1) ss += __shfl_xor(ss, m, 64);
  float scale = 0.97467943448089633f / fmaxf(sqrtf(ss), 1e-12f);   // sqrt(0.95)
  ushort4 o;
  o.x = f2bf(raw.x*scale); o.y = f2bf(raw.y*scale);
  o.z = f2bf(raw.z*scale); o.w = f2bf(raw.w*scale);
  *(ushort4*)(Zb + (size_t)row * C_TOT + c0) = o;
  *(float4*)(out_nf + (size_t)row * C_F + c0) = raw;

  // PE: lanes 0..31 each produce one of the 32 pe elements for this row.
  // layout: pe[d*8 + s*4 + f], d=dim, s=0 sin / 1 cos, f=freq
  const float* csrc = (row < B_CUR) ? (coords + (size_t)row * 4)
                                    : (hcoords + (size_t)(row - B_CUR) * 4);
  int d = lane >> 3, sc = (lane >> 2) & 1, f = lane & 3;
  float c = csrc[d & 3];
  float ang = c * 6.283185307179586f * (float)(1 << f);
  float pe = sc ? cosf(ang) : sinf(ang);
  // sum of squares across the 32 pe lanes (lanes 32..63 mirror lanes 0..31)
  float p2 = pe * pe;
  #pragma unroll
  for (int m = 16; m; m >>= 1) p2 += __shfl_xor(p2, m, 64);
  float pscale = 0.22360679774997896f / fmaxf(sqrtf(p2), 1e-12f); // sqrt(0.05)
  if (lane < 32) Zb[(size_t)row * C_TOT + C_F + lane] = f2bf(pe * pscale);
}

// K3: S = Zb Zb^T, symmetric: only upper-triangle 128x128 tiles computed
//     (2080 blocks); off-diag tiles mirrored via a 2nd transposed repack.
#define EP_STRIDE 136
__global__ __launch_bounds__(256) void k_gemm_mfma(const u16* __restrict__ Zb,
                                                   u16* __restrict__ adj16) {
  __shared__ __align__(16) u16 smem[2 * 128 * 96];     // 49152 B
  u16* As = smem;               // [128][96] u16
  u16* Bs = smem + 128 * 96;    // [128][96] u16
  int tid  = threadIdx.x;

  int t = blockIdx.x;
  int bi = (int)floorf(((2.0f*NTILE + 1.0f) -
            sqrtf((float)((2*NTILE+1)*(2*NTILE+1)) - 8.0f*(float)t)) * 0.5f);
  if (bi < 0) bi = 0; if (bi > NTILE-1) bi = NTILE-1;
  while (bi > 0 && t < bi*NTILE - bi*(bi-1)/2) --bi;
  while (bi < NTILE-1 && t >= (bi+1)*NTILE - (bi+1)*bi/2) ++bi;
  int bj = bi + (t - (bi*NTILE - bi*(bi-1)/2));

  int wave = tid >> 6, lane = tid & 63;
  int quad = lane >> 4, l16 = lane & 15;
  int m0w  = (wave >> 1) * 64;
  int n0w  = (wave & 1) * 64;
  int i0   = bi * 128, j0 = bj * 128;

  floatx4 acc[4][4];
  #pragma unroll
  for (int a = 0; a < 4; ++a)
    #pragma unroll
    for (int b = 0; b < 4; ++b) acc[a][b] = (floatx4){0.f, 0.f, 0.f, 0.f};

  for (int kt = 0; kt < C_TOT; kt += 96) {
    #pragma unroll
    for (int it = 0; it < 6; ++it) {
      int s   = it * 256 + tid;
      int row = s / 12, seg = s % 12;
      const u16* ga = Zb + (size_t)(i0 + row) * C_TOT + kt + seg * 8;
      const u16* gb = Zb + (size_t)(j0 + row) * C_TOT + kt + seg * 8;
      GLD_LDS16(ga, As + s * 8);
      GLD_LDS16(gb, Bs + s * 8);
    }
    __builtin_amdgcn_s_waitcnt(0);
    __syncthreads();
    #pragma unroll
    for (int ks = 0; ks < 3; ++ks) {
      short8 af[4], bf[4];
      #pragma unroll
      for (int mi = 0; mi < 4; ++mi)
        af[mi] = *(const short8*)(&As[(m0w + mi*16 + l16) * 96 + ks*32 + quad*8]);
      #pragma unroll
      for (int ni = 0; ni < 4; ++ni)
        bf[ni] = *(const short8*)(&Bs[(n0w + ni*16 + l16) * 96 + ks*32 + quad*8]);
      #pragma unroll
      for (int mi = 0; mi < 4; ++mi)
        #pragma unroll
        for (int ni = 0; ni < 4; ++ni)
          acc[mi][ni] = __builtin_amdgcn_mfma_f32_16x16x32_bf16(
              af[mi], bf[ni], acc[mi][ni], 0, 0, 0);
    }
    __syncthreads();
  }

  float w = ((bi < 32) != (bj < 32)) ? 0.5f : 1.0f;

  #pragma unroll
  for (int mi = 0; mi < 4; ++mi) {
    #pragma unroll
    for (int ni = 0; ni < 4; ++ni) {
      int col = n0w + ni * 16 + l16;
      #pragma unroll
      for (int rg = 0; rg < 4; ++rg) {
        int row = m0w + mi * 16 + quad * 4 + rg;
        smem[row * EP_STRIDE + col] = f2bf(acc[mi][ni][rg] * w);
      }
    }
  }
  __syncthreads();
  #pragma unroll
  for (int it = 0; it < 8; ++it) {
    int idx = it * 256 + tid;
    int row = idx >> 4, l = idx & 15;
    uint4 v = *(const uint4*)(&smem[row * EP_STRIDE + l * 8]);
    *(uint4*)(&adj16[(size_t)(i0 + row) * 16384 + j0 + l * 8]) = v;
  }

  if (bi != bj) {
    __syncthreads();
    #pragma unroll
    for (int mi = 0; mi < 4; ++mi) {
      #pragma unroll
      for (int ni = 0; ni < 4; ++ni) {
        int col = n0w + ni * 16 + l16;
        #pragma unroll
        for (int rg = 0; rg < 4; ++rg) {
          int row = m0w + mi * 16 + quad * 4 + rg;
          smem[col * EP_STRIDE + row] = f2bf(acc[mi][ni][rg] * w);
        }
      }
    }
    __syncthreads();
    #pragma unroll
    for (int it = 0; it < 8; ++it) {
      int idx = it * 256 + tid;
      int row = idx >> 4, l = idx & 15;
      uint4 v = *(const uint4*)(&smem[row * EP_STRIDE + l * 8]);
      *(uint4*)(&adj16[(size_t)(j0 + row) * 16384 + i0 + l * 8]) = v;
    }
  }
}

// K4: per-row top-16 (packed u32 keys, wave-local top-16 + single merge) AND
//     zero-fill of the row's f32 output (overlaps with selection compute).
#define TOP2(x) { unsigned int xv_ = (x); \
  if (xv_ > m1) { m2 = m1; m1 = xv_; } else if (xv_ > m2) { m2 = xv_; } }

__global__ __launch_bounds__(256) void k_topk(
    const u16* __restrict__ adj16, float* __restrict__ adj,
    int* __restrict__ topk_idx, float* __restrict__ topk_val,
    float* __restrict__ deg_out) {
  __shared__ unsigned int keys[N_TOT];   // 32 KB
  __shared__ unsigned int cand[64];
  __shared__ float s_diag;
  int r = blockIdx.x;
  int t = threadIdx.x;
  int wave = t >> 6, lane = t & 63;
  const u16* rowp = adj16 + (size_t)r * 16384;

  #pragma unroll
  for (int it = 0; it < 4; ++it) {
    int c0 = it * 2048 + t * 8;
    uint4 v = *(const uint4*)(rowp + c0);
    u16 e[8]; *(uint4*)e = v;
    unsigned int kk[8];
    #pragma unroll
    for (int q = 0; q < 8; ++q) {
      unsigned int b = e[q];
      unsigned int s16 = (b & 0x8000u) ? (b ^ 0xFFFFu) : (b | 0x8000u);
      kk[q] = (s16 << 16) | (unsigned int)(8191 - (c0 + q));
    }
    *(uint4*)(&keys[c0])     = *(uint4*)(&kk[0]);
    *(uint4*)(&keys[c0 + 4]) = *(uint4*)(&kk[4]);
  }
  __syncthreads();
  if (t == 0) {
    s_diag = bf2f(rowp[r]);
    keys[r] = 0xFFFF0000u | (unsigned int)(8191 - r);
  }
  __syncthreads();
  float diagval = s_diag;

  // bf16 row fully staged -> safe to zero the overlapping f32 output row now.
  // Stores drain while the LDS-only selection below runs.
  {
    float* oro = adj + (size_t)r * N_TOT;
    const float4 z4 = make_float4(0.f, 0.f, 0.f, 0.f);
    #pragma unroll
    for (int kk2 = 0; kk2 < 8; ++kk2)
      *(float4*)(oro + kk2 * 1024 + t * 4) = z4;
  }

  unsigned int m1 = 0, m2 = 0;
  int base = wave * 2048 + lane * 4;
  #pragma unroll
  for (int j = 0; j < 8; ++j) {
    uint4 v = *(const uint4*)(&keys[base + j * 256]);
    TOP2(v.x) TOP2(v.y) TOP2(v.z) TOP2(v.w)
  }

  for (int it = 0; it < KSEL; ++it) {
    unsigned int wmax = m1;
    #pragma unroll
    for (int s = 32; s; s >>= 1) {
      unsigned int o = (unsigned int)__shfl_xor((int)wmax, s, 64);
      wmax = (o > wmax) ? o : wmax;
    }
    if (lane == it) cand[wave * 16 + it] = wmax;
    if (m1 == wmax) {
      int col = 8191 - (int)(wmax & 0x1FFFu);
      keys[col] = 0;
      if (m2 != 0) { m1 = m2; m2 = 0; }
      else {
        m1 = 0; m2 = 0;
        #pragma unroll
        for (int j = 0; j < 8; ++j) {
          uint4 v = *(const uint4*)(&keys[base + j * 256]);
          TOP2(v.x) TOP2(v.y) TOP2(v.z) TOP2(v.w)
        }
      }
    }
  }
  __syncthreads();

  if (wave == 0) {
    unsigned int c = cand[lane];
    unsigned int myWin = 0;
    for (int it = 0; it < KSEL; ++it) {
      unsigned int wmax = c;
      #pragma unroll
      for (int s = 32; s; s >>= 1) {
        unsigned int o = (unsigned int)__shfl_xor((int)wmax, s, 64);
        wmax = (o > wmax) ? o : wmax;
      }
      if (c == wmax) c = 0;
      if (lane == it) myWin = wmax;
    }
    float val = 0.f;
    int col = 0;
    if (lane < KSEL) {
      unsigned int p = myWin;
      col = 8191 - (int)(p & 0x1FFFu);
      unsigned int k16 = p >> 16;
      unsigned int b = (k16 & 0x8000u) ? (k16 ^ 0x8000u) : ((~k16) & 0xFFFFu);
      val = (col == r) ? diagval : bf2f((u16)b);
      topk_idx[r * KSEL + lane] = col;
      topk_val[r * KSEL + lane] = val;
    }
    float s = (lane < KSEL) ? val : 0.f;
    #pragma unroll
    for (int m = 8; m; m >>= 1) s += __shfl_xor(s, m, 64);
    if (lane == 0) deg_out[r] = s;
  }
}

// K5: scatter the 16 scaled entries per row (zeros already written by k_topk).
__global__ void k_scale(float* __restrict__ adj, const int* __restrict__ topk_idx,
                        const float* __restrict__ topk_val,
                        const float* __restrict__ deg) {
  int g = blockIdx.x * blockDim.x + threadIdx.x;
  if (g >= N_TOT * KSEL) return;
  int r = g >> 4, m = g & 15;
  int j = topk_idx[r * KSEL + m];
  if (j < 0) j = 0; if (j >= N_TOT) j = N_TOT - 1;   // insurance
  float v = topk_val[r * KSEL + m];
  float di = 1.0f / sqrtf(fmaxf(deg[r], 1e-12f));
  float dj = 1.0f / sqrtf(fmaxf(deg[j], 1e-12f));
  adj[(size_t)r * N_TOT + j] = v * di * dj;
}

extern "C" void kernel_launch(void* const* d_in, const int* in_sizes, int n_in,
                              void* d_out, int out_size, void* d_ws, size_t ws_size,
                              hipStream_t stream) {
  const float* feats   = (const float*)d_in[0];
  const float* coords  = (const float*)d_in[1];
  const float* hfeats  = (const float*)d_in[2];
  const float* hcoords = (const float*)d_in[3];
  float* out    = (float*)d_out;
  float* adj    = out;                               // [8192, 8192] f32
  u16*   adj16  = (u16*)out;                         // bf16 S packed per-row
  float* out_nf = out + (size_t)N_TOT * N_TOT;       // [8192, 256]  f32

  char* ws    = (char*)d_ws;
  u16*  Zb    = (u16*)ws;
  size_t zb   = (size_t)N_TOT * C_TOT * sizeof(u16);
  zb = (zb + 255) & ~(size_t)255;
  int*   t_idx = (int*)(ws + zb);
  float* t_val = (float*)(ws + zb + (size_t)N_TOT*KSEL*sizeof(int));
  float* deg   = (float*)(ws + zb + (size_t)N_TOT*KSEL*(sizeof(int)+sizeof(float)));

  hipLaunchKernelGGL(k_prep, dim3(N_TOT/4), dim3(256), 0, stream,
                     feats, hfeats, coords, hcoords, Zb, out_nf);
  hipLaunchKernelGGL(k_gemm_mfma, dim3(NTILE*(NTILE+1)/2), dim3(256), 0, stream,
                     Zb, adj16);
  hipLaunchKernelGGL(k_topk, dim3(N_TOT), dim3(256), 0, stream,
                     adj16, adj, t_idx, t_val, deg);
  hipLaunchKernelGGL(k_scale, dim3((N_TOT*KSEL + 255)/256), dim3(256), 0, stream,
                     adj, t_idx, t_val, deg);
}

// Round 12
// 386.685 us; speedup vs baseline: 4.3425x; 1.0366x over previous
//
#include <hip/hip_runtime.h>
#include <math.h>

#define B_CUR 4096
#define N_TOT 8192
#define C_F   256
#define C_TOT 288
#define KSEL  16
#define NTILE 64    // 8192 / 128

typedef unsigned short u16;
typedef __attribute__((ext_vector_type(8))) short short8;
typedef __attribute__((ext_vector_type(4))) float floatx4;

__device__ inline float bf2f(u16 v) {
  union { unsigned int u; float f; } x; x.u = ((unsigned int)v) << 16; return x.f;
}
__device__ inline u16 f2bf(float f) {
  union { float f; unsigned int u; } x; x.f = f;
  unsigned int u = x.u;
  u += ((u >> 16) & 1u) + 0x7FFFu;   // RNE
  return (u16)(u >> 16);
}

#define GLD_LDS16(g, l) __builtin_amdgcn_global_load_lds(                      \
    (const __attribute__((address_space(1))) unsigned int*)(g),                \
    (__attribute__((address_space(3))) unsigned int*)(l), 16, 0, 0)

// K1 (fused): per wave = one row. Feature normalize (64 lanes) + PE (32 lanes).
__global__ __launch_bounds__(256) void k_prep(
    const float* __restrict__ feats, const float* __restrict__ hfeats,
    const float* __restrict__ coords, const float* __restrict__ hcoords,
    u16* __restrict__ Zb, float* __restrict__ out_nf) {
  int wave = threadIdx.x >> 6;
  int lane = threadIdx.x & 63;
  int row  = blockIdx.x * 4 + wave;
  const float* src = (row < B_CUR) ? (feats + (size_t)row * C_F)
                                   : (hfeats + (size_t)(row - B_CUR) * C_F);
  int c0 = lane * 4;
  float4 raw = *(const float4*)(src + c0);
  float ss = raw.x*raw.x + raw.y*raw.y + raw.z*raw.z + raw.w*raw.w;
  #pragma unroll
  for (int m = 32; m; m >>= 1) ss += __shfl_xor(ss, m, 64);
  float scale = 0.97467943448089633f / fmaxf(sqrtf(ss), 1e-12f);   // sqrt(0.95)
  ushort4 o;
  o.x = f2bf(raw.x*scale); o.y = f2bf(raw.y*scale);
  o.z = f2bf(raw.z*scale); o.w = f2bf(raw.w*scale);
  *(ushort4*)(Zb + (size_t)row * C_TOT + c0) = o;
  *(float4*)(out_nf + (size_t)row * C_F + c0) = raw;

  const float* csrc = (row < B_CUR) ? (coords + (size_t)row * 4)
                                    : (hcoords + (size_t)(row - B_CUR) * 4);
  int d = lane >> 3, sc = (lane >> 2) & 1, f = lane & 3;
  float c = csrc[d & 3];
  float ang = c * 6.283185307179586f * (float)(1 << f);
  float pe = sc ? cosf(ang) : sinf(ang);
  float p2 = pe * pe;
  #pragma unroll
  for (int m = 16; m; m >>= 1) p2 += __shfl_xor(p2, m, 64);
  float pscale = 0.22360679774997896f / fmaxf(sqrtf(p2), 1e-12f); // sqrt(0.05)
  if (lane < 32) Zb[(size_t)row * C_TOT + C_F + lane] = f2bf(pe * pscale);
}

// K3: S = Zb Zb^T, symmetric: upper-triangle tiles only, mirrored epilogue.
#define EP_STRIDE 136
__global__ __launch_bounds__(256) void k_gemm_mfma(const u16* __restrict__ Zb,
                                                   u16* __restrict__ adj16) {
  __shared__ __align__(16) u16 smem[2 * 128 * 96];     // 49152 B
  u16* As = smem;
  u16* Bs = smem + 128 * 96;
  int tid  = threadIdx.x;

  int t = blockIdx.x;
  int bi = (int)floorf(((2.0f*NTILE + 1.0f) -
            sqrtf((float)((2*NTILE+1)*(2*NTILE+1)) - 8.0f*(float)t)) * 0.5f);
  if (bi < 0) bi = 0; if (bi > NTILE-1) bi = NTILE-1;
  while (bi > 0 && t < bi*NTILE - bi*(bi-1)/2) --bi;
  while (bi < NTILE-1 && t >= (bi+1)*NTILE - (bi+1)*bi/2) ++bi;
  int bj = bi + (t - (bi*NTILE - bi*(bi-1)/2));

  int wave = tid >> 6, lane = tid & 63;
  int quad = lane >> 4, l16 = lane & 15;
  int m0w  = (wave >> 1) * 64;
  int n0w  = (wave & 1) * 64;
  int i0   = bi * 128, j0 = bj * 128;

  floatx4 acc[4][4];
  #pragma unroll
  for (int a = 0; a < 4; ++a)
    #pragma unroll
    for (int b = 0; b < 4; ++b) acc[a][b] = (floatx4){0.f, 0.f, 0.f, 0.f};

  for (int kt = 0; kt < C_TOT; kt += 96) {
    #pragma unroll
    for (int it = 0; it < 6; ++it) {
      int s   = it * 256 + tid;
      int row = s / 12, seg = s % 12;
      const u16* ga = Zb + (size_t)(i0 + row) * C_TOT + kt + seg * 8;
      const u16* gb = Zb + (size_t)(j0 + row) * C_TOT + kt + seg * 8;
      GLD_LDS16(ga, As + s * 8);
      GLD_LDS16(gb, Bs + s * 8);
    }
    __builtin_amdgcn_s_waitcnt(0);
    __syncthreads();
    #pragma unroll
    for (int ks = 0; ks < 3; ++ks) {
      short8 af[4], bf[4];
      #pragma unroll
      for (int mi = 0; mi < 4; ++mi)
        af[mi] = *(const short8*)(&As[(m0w + mi*16 + l16) * 96 + ks*32 + quad*8]);
      #pragma unroll
      for (int ni = 0; ni < 4; ++ni)
        bf[ni] = *(const short8*)(&Bs[(n0w + ni*16 + l16) * 96 + ks*32 + quad*8]);
      #pragma unroll
      for (int mi = 0; mi < 4; ++mi)
        #pragma unroll
        for (int ni = 0; ni < 4; ++ni)
          acc[mi][ni] = __builtin_amdgcn_mfma_f32_16x16x32_bf16(
              af[mi], bf[ni], acc[mi][ni], 0, 0, 0);
    }
    __syncthreads();
  }

  float w = ((bi < 32) != (bj < 32)) ? 0.5f : 1.0f;

  #pragma unroll
  for (int mi = 0; mi < 4; ++mi) {
    #pragma unroll
    for (int ni = 0; ni < 4; ++ni) {
      int col = n0w + ni * 16 + l16;
      #pragma unroll
      for (int rg = 0; rg < 4; ++rg) {
        int row = m0w + mi * 16 + quad * 4 + rg;
        smem[row * EP_STRIDE + col] = f2bf(acc[mi][ni][rg] * w);
      }
    }
  }
  __syncthreads();
  #pragma unroll
  for (int it = 0; it < 8; ++it) {
    int idx = it * 256 + tid;
    int row = idx >> 4, l = idx & 15;
    uint4 v = *(const uint4*)(&smem[row * EP_STRIDE + l * 8]);
    *(uint4*)(&adj16[(size_t)(i0 + row) * 16384 + j0 + l * 8]) = v;
  }

  if (bi != bj) {
    __syncthreads();
    #pragma unroll
    for (int mi = 0; mi < 4; ++mi) {
      #pragma unroll
      for (int ni = 0; ni < 4; ++ni) {
        int col = n0w + ni * 16 + l16;
        #pragma unroll
        for (int rg = 0; rg < 4; ++rg) {
          int row = m0w + mi * 16 + quad * 4 + rg;
          smem[col * EP_STRIDE + row] = f2bf(acc[mi][ni][rg] * w);
        }
      }
    }
    __syncthreads();
    #pragma unroll
    for (int it = 0; it < 8; ++it) {
      int idx = it * 256 + tid;
      int row = idx >> 4, l = idx & 15;
      uint4 v = *(const uint4*)(&smem[row * EP_STRIDE + l * 8]);
      *(uint4*)(&adj16[(size_t)(j0 + row) * 16384 + i0 + l * 8]) = v;
    }
  }
}

// K4: per-row top-16, register-resident selection. adj16/adj ALIAS (same buffer):
//     no __restrict__ on them, and a __syncthreads() separates the row reads
//     (into registers) from the f32 zero-stores — loads drained block-wide first.
__global__ __launch_bounds__(256) void k_topk(
    const u16* adj16, float* adj,
    int* __restrict__ topk_idx, float* __restrict__ topk_val,
    float* __restrict__ deg_out) {
  __shared__ unsigned int cand[64];
  __shared__ float s_diag;
  int r = blockIdx.x;
  int t = threadIdx.x;
  int wave = t >> 6, lane = t & 63;
  const u16* rowp = adj16 + (size_t)r * 16384;

  // 1) read the whole row into registers (4 x 16B per thread) + diag
  uint4 raw[4];
  #pragma unroll
  for (int j = 0; j < 4; ++j)
    raw[j] = *(const uint4*)(rowp + j * 2048 + t * 8);
  if (t == 0) s_diag = bf2f(rowp[r]);
  __syncthreads();   // vmcnt(0)+barrier: ALL reads done before ANY zero-store

  // 2) zero the f32 output row; stores drain during register-only selection.
  {
    float* oro = adj + (size_t)r * N_TOT;
    const float4 z4 = make_float4(0.f, 0.f, 0.f, 0.f);
    #pragma unroll
    for (int kk = 0; kk < 8; ++kk)
      *(float4*)(oro + kk * 1024 + t * 4) = z4;
  }

  // 3) build packed keys in registers.
  //    key: high16 = sortable bf16, low13 = 8191-col (lowest col wins ties)
  unsigned int keys[32];
  #pragma unroll
  for (int j = 0; j < 4; ++j) {
    int c0 = j * 2048 + t * 8;
    u16 e[8]; *(uint4*)e = raw[j];
    #pragma unroll
    for (int q = 0; q < 8; ++q) {
      int col = c0 + q;
      unsigned int b = e[q];
      unsigned int s16 = (b & 0x8000u) ? (b ^ 0xFFFFu) : (b | 0x8000u);
      unsigned int k = (s16 << 16) | (unsigned int)(8191 - col);
      if (col == r) k = 0xFFFF0000u | (unsigned int)(8191 - r);  // forced max
      keys[j * 8 + q] = k;
    }
  }

  // 4) per-thread top-2 (with slot indices)
  unsigned int m1 = 0, m2 = 0; int i1 = 0, i2 = 0;
  #pragma unroll
  for (int i = 0; i < 32; ++i) {
    unsigned int k = keys[i];
    if (k > m1) { m2 = m1; i2 = i1; m1 = k; i1 = i; }
    else if (k > m2) { m2 = k; i2 = i; }
  }
  unsigned int taken = 0;

  // 5) wave-local top-16, zero barriers, zero LDS traffic in the loop
  for (int it = 0; it < KSEL; ++it) {
    unsigned int wmax = m1;
    #pragma unroll
    for (int s = 32; s; s >>= 1) {
      unsigned int o = (unsigned int)__shfl_xor((int)wmax, s, 64);
      wmax = (o > wmax) ? o : wmax;
    }
    if (lane == it) cand[wave * 16 + it] = wmax;
    if (m1 == wmax && m1 != 0) {          // unique owner (keys unique)
      taken |= 1u << i1;
      if (m2 != 0) { m1 = m2; i1 = i2; m2 = 0; }
      else {                               // masked in-register rescan
        m1 = 0; m2 = 0; i1 = 0; i2 = 0;
        #pragma unroll
        for (int i = 0; i < 32; ++i) {
          unsigned int k = (taken & (1u << i)) ? 0u : keys[i];
          if (k > m1) { m2 = m1; i2 = i1; m1 = k; i1 = i; }
          else if (k > m2) { m2 = k; i2 = i; }
        }
      }
    }
  }
  __syncthreads();

  // 6) wave 0 merges 64 candidates -> global top-16, writes outputs
  if (wave == 0) {
    unsigned int c = cand[lane];
    unsigned int myWin = 0;
    for (int it = 0; it < KSEL; ++it) {
      unsigned int wmax = c;
      #pragma unroll
      for (int s = 32; s; s >>= 1) {
        unsigned int o = (unsigned int)__shfl_xor((int)wmax, s, 64);
        wmax = (o > wmax) ? o : wmax;
      }
      if (c == wmax) c = 0;
      if (lane == it) myWin = wmax;
    }
    float val = 0.f;
    int col = 0;
    if (lane < KSEL) {
      unsigned int p = myWin;
      col = 8191 - (int)(p & 0x1FFFu);
      unsigned int k16 = p >> 16;
      unsigned int b = (k16 & 0x8000u) ? (k16 ^ 0x8000u) : ((~k16) & 0xFFFFu);
      val = (col == r) ? s_diag : bf2f((u16)b);
      topk_idx[r * KSEL + lane] = col;
      topk_val[r * KSEL + lane] = val;
    }
    float s = (lane < KSEL) ? val : 0.f;
    #pragma unroll
    for (int m = 8; m; m >>= 1) s += __shfl_xor(s, m, 64);
    if (lane == 0) deg_out[r] = s;
  }
}

// K5: scatter the 16 scaled entries per row (zeros already written by k_topk).
__global__ void k_scale(float* __restrict__ adj, const int* __restrict__ topk_idx,
                        const float* __restrict__ topk_val,
                        const float* __restrict__ deg) {
  int g = blockIdx.x * blockDim.x + threadIdx.x;
  if (g >= N_TOT * KSEL) return;
  int r = g >> 4, m = g & 15;
  int j = topk_idx[r * KSEL + m];
  if (j < 0) j = 0; if (j >= N_TOT) j = N_TOT - 1;   // insurance
  float v = topk_val[r * KSEL + m];
  float di = 1.0f / sqrtf(fmaxf(deg[r], 1e-12f));
  float dj = 1.0f / sqrtf(fmaxf(deg[j], 1e-12f));
  adj[(size_t)r * N_TOT + j] = v * di * dj;
}

extern "C" void kernel_launch(void* const* d_in, const int* in_sizes, int n_in,
                              void* d_out, int out_size, void* d_ws, size_t ws_size,
                              hipStream_t stream) {
  const float* feats   = (const float*)d_in[0];
  const float* coords  = (const float*)d_in[1];
  const float* hfeats  = (const float*)d_in[2];
  const float* hcoords = (const float*)d_in[3];
  float* out    = (float*)d_out;
  float* adj    = out;                               // [8192, 8192] f32
  u16*   adj16  = (u16*)out;                         // bf16 S packed per-row
  float* out_nf = out + (size_t)N_TOT * N_TOT;       // [8192, 256]  f32

  char* ws    = (char*)d_ws;
  u16*  Zb    = (u16*)ws;
  size_t zb   = (size_t)N_TOT * C_TOT * sizeof(u16);
  zb = (zb + 255) & ~(size_t)255;
  int*   t_idx = (int*)(ws + zb);
  float* t_val = (float*)(ws + zb + (size_t)N_TOT*KSEL*sizeof(int));
  float* deg   = (float*)(ws + zb + (size_t)N_TOT*KSEL*(sizeof(int)+sizeof(float)));

  hipLaunchKernelGGL(k_prep, dim3(N_TOT/4), dim3(256), 0, stream,
                     feats, hfeats, coords, hcoords, Zb, out_nf);
  hipLaunchKernelGGL(k_gemm_mfma, dim3(NTILE*(NTILE+1)/2), dim3(256), 0, stream,
                     Zb, adj16);
  hipLaunchKernelGGL(k_topk, dim3(N_TOT), dim3(256), 0, stream,
                     adj16, adj, t_idx, t_val, deg);
  hipLaunchKernelGGL(k_scale, dim3((N_TOT*KSEL + 255)/256), dim3(256), 0, stream,
                     adj, t_idx, t_val, deg);
}